// Round 19
// baseline (709.809 us; speedup 1.0000x reference)
//
#include <hip/hip_runtime.h>

#define NSEQ 32768
#define NB 8
#define NC 16
#define LBLK 1024          // layer0 grid (NB*NSEQ/256)
#define LPX (LBLK / 8)     // layer0 logical blocks per XCD = 128
#define QGRD 4096          // gated-layer grid (NB*NSEQ/64), 4 threads/position
#define QPX (QGRD / 8)     // gated-layer logical blocks per XCD = 512

typedef float vfloat4 __attribute__((ext_vector_type(4)));   // native vec for nontemporal builtin

__device__ __forceinline__ float sigm_f(float x) {
    return __fdividef(1.f, 1.f + __expf(-x));
}
__device__ __forceinline__ float tanh_f(float x) {
    return __fdividef(2.f, 1.f + __expf(-2.f * x)) - 1.f;
}

__device__ __forceinline__ void nt_store4(float* p, float a, float b, float c, float d) {
    vfloat4 v; v.x = a; v.y = b; v.z = c; v.w = d;
    __builtin_nontemporal_store(v, (vfloat4*)p);
}

// Layer 0 (byte-identical to round 18 — FROZEN)
__global__ __launch_bounds__(256) void k_layer0(
    const float* __restrict__ x, const float* __restrict__ w0,
    const float* __restrict__ b0, float* __restrict__ h)
{
    int bid = blockIdx.x;
    int tid = ((bid & 7) * LPX + (bid >> 3)) * 256 + threadIdx.x;
    int n = tid & (NSEQ - 1);
    const float inv = 1.f / 32768.f;
    float xc = x[tid] * inv;
    float xp = (n >= 1) ? x[tid - 1] * inv : 0.f;
    float v[NC];
#pragma unroll
    for (int c = 0; c < NC; c++) {
        float o = w0[c * 2] * xp + w0[c * 2 + 1] * xc + b0[c];
        v[c] = xc + o;
    }
    float* ph = h + (size_t)tid * NC;
#pragma unroll
    for (int i = 0; i < 4; i++)
        nt_store4(ph + i * 4, v[i * 4], v[i * 4 + 1], v[i * 4 + 2], v[i * 4 + 3]);
}

// Gated layer (byte-identical to round 18 — FROZEN)
__global__ __launch_bounds__(256, 6) void k_layer(
    const float* __restrict__ hin, float* __restrict__ hout,
    const float* __restrict__ wf, const float* __restrict__ bf,
    const float* __restrict__ wg, const float* __restrict__ bg, int d)
{
    int bid = blockIdx.x;
    int lbid = (bid & 7) * QPX + (bid >> 3);          // XCD swizzle: batch b -> XCD b
    int t = threadIdx.x;
    int pos = lbid * 64 + (t & 63);                   // position over B*N
    int q = __builtin_amdgcn_readfirstlane(t >> 6);   // channel quarter 0..3
    int n = pos & (NSEQ - 1);

    float hc[NC], hp[NC];
    {
        const float4* pc = (const float4*)(hin + (size_t)pos * NC);
#pragma unroll
        for (int i = 0; i < 4; i++) {
            float4 tv = pc[i];
            hc[i * 4] = tv.x; hc[i * 4 + 1] = tv.y; hc[i * 4 + 2] = tv.z; hc[i * 4 + 3] = tv.w;
        }
    }
    if (n >= d) {
        const float4* pp = (const float4*)(hin + (size_t)(pos - d) * NC);
#pragma unroll
        for (int i = 0; i < 4; i++) {
            float4 tv = pp[i];
            hp[i * 4] = tv.x; hp[i * 4 + 1] = tv.y; hp[i * 4 + 2] = tv.z; hp[i * 4 + 3] = tv.w;
        }
    } else {
#pragma unroll
        for (int i = 0; i < NC; i++) hp[i] = 0.f;
    }

    const int c0 = q * 4;
    float f[4], g[4];
#pragma unroll
    for (int j = 0; j < 4; j++) { f[j] = bf[c0 + j]; g[j] = bg[c0 + j]; }

#pragma unroll
    for (int ci = 0; ci < NC; ci++) {
        float xp = hp[ci], xc = hc[ci];
#pragma unroll
        for (int j = 0; j < 4; j++) {
            int co = c0 + j;
            // weights wave-uniform -> scalar loads, SGPR operand per v_fma
            f[j] = fmaf(wf[(co * NC + ci) * 2 + 0], xp, f[j]);
            f[j] = fmaf(wf[(co * NC + ci) * 2 + 1], xc, f[j]);
            g[j] = fmaf(wg[(co * NC + ci) * 2 + 0], xp, g[j]);
            g[j] = fmaf(wg[(co * NC + ci) * 2 + 1], xc, g[j]);
        }
    }

    float v[4];
#pragma unroll
    for (int j = 0; j < 4; j++) {
        float outv = tanh_f(f[j]) * sigm_f(g[j]);
        v[j] = hc[c0 + j] + outv;
    }
    nt_store4(hout + (size_t)pos * NC + c0, v[0], v[1], v[2], v[3]);
}

// Fused pair (A,B), dB <= 16: layer A computed EXACTLY for 64+dB positions
// (inputs from global — zero garbage), staged in LDS; layer B reads LDS.
// Per-position math text verbatim from k_layer for both sub-layers.
__global__ __launch_bounds__(256, 5) void k_pair(
    const float* __restrict__ hin, float* __restrict__ hout,
    const float* __restrict__ wfA, const float* __restrict__ bfA,
    const float* __restrict__ wgA, const float* __restrict__ bgA, int dA,
    const float* __restrict__ wfB, const float* __restrict__ bfB,
    const float* __restrict__ wgB, const float* __restrict__ bgB, int dB)
{
    __shared__ float hsA[NC][80];     // 16 x (64 + dB<=16) = 5 KB
    int bid = blockIdx.x;
    int lbid = (bid & 7) * QPX + (bid >> 3);          // XCD swizzle
    int t = threadIdx.x;
    int lane = t & 63;
    int q = __builtin_amdgcn_readfirstlane(t >> 6);   // channel quarter 0..3
    const int c0 = q * 4;
    int P = lbid * 64;                                // tile start, flat pos
    int n0 = P & (NSEQ - 1);                          // tile start within seq

    // ---- layer A: pass 0 = halo (P-dB..P-1), pass 1 = main (P..P+63) ------
#pragma unroll 1
    for (int pass = 0; pass < 2; ++pass) {
        int pos  = pass ? (P + lane) : (P - dB + lane);
        int act  = pass ? 1 : ((lane < dB) && (n0 > 0));
        int slot = pass ? (dB + lane) : lane;
        if (act) {
            int n = pos & (NSEQ - 1);
            float hc[NC], hp[NC];
            {
                const float4* pc = (const float4*)(hin + (size_t)pos * NC);
#pragma unroll
                for (int i = 0; i < 4; i++) {
                    float4 tv = pc[i];
                    hc[i * 4] = tv.x; hc[i * 4 + 1] = tv.y; hc[i * 4 + 2] = tv.z; hc[i * 4 + 3] = tv.w;
                }
            }
            if (n >= dA) {
                const float4* pp = (const float4*)(hin + (size_t)(pos - dA) * NC);
#pragma unroll
                for (int i = 0; i < 4; i++) {
                    float4 tv = pp[i];
                    hp[i * 4] = tv.x; hp[i * 4 + 1] = tv.y; hp[i * 4 + 2] = tv.z; hp[i * 4 + 3] = tv.w;
                }
            } else {
#pragma unroll
                for (int i = 0; i < NC; i++) hp[i] = 0.f;
            }

            float f[4], g[4];
#pragma unroll
            for (int j = 0; j < 4; j++) { f[j] = bfA[c0 + j]; g[j] = bgA[c0 + j]; }

#pragma unroll
            for (int ci = 0; ci < NC; ci++) {
                float xp = hp[ci], xc = hc[ci];
#pragma unroll
                for (int j = 0; j < 4; j++) {
                    int co = c0 + j;
                    f[j] = fmaf(wfA[(co * NC + ci) * 2 + 0], xp, f[j]);
                    f[j] = fmaf(wfA[(co * NC + ci) * 2 + 1], xc, f[j]);
                    g[j] = fmaf(wgA[(co * NC + ci) * 2 + 0], xp, g[j]);
                    g[j] = fmaf(wgA[(co * NC + ci) * 2 + 1], xc, g[j]);
                }
            }

#pragma unroll
            for (int j = 0; j < 4; j++) {
                float outv = tanh_f(f[j]) * sigm_f(g[j]);
                hsA[c0 + j][slot] = hc[c0 + j] + outv;
            }
        }
    }
    __syncthreads();

    // ---- layer B from LDS (values identical to a global round-trip) --------
    {
        int pos = P + lane;
        int n = pos & (NSEQ - 1);
        float hc[NC], hp[NC];
#pragma unroll
        for (int c = 0; c < NC; c++) hc[c] = hsA[c][dB + lane];
        if (n >= dB) {
#pragma unroll
            for (int c = 0; c < NC; c++) hp[c] = hsA[c][lane];
        } else {
#pragma unroll
            for (int c = 0; c < NC; c++) hp[c] = 0.f;
        }

        float f[4], g[4];
#pragma unroll
        for (int j = 0; j < 4; j++) { f[j] = bfB[c0 + j]; g[j] = bgB[c0 + j]; }

#pragma unroll
        for (int ci = 0; ci < NC; ci++) {
            float xp = hp[ci], xc = hc[ci];
#pragma unroll
            for (int j = 0; j < 4; j++) {
                int co = c0 + j;
                f[j] = fmaf(wfB[(co * NC + ci) * 2 + 0], xp, f[j]);
                f[j] = fmaf(wfB[(co * NC + ci) * 2 + 1], xc, f[j]);
                g[j] = fmaf(wgB[(co * NC + ci) * 2 + 0], xp, g[j]);
                g[j] = fmaf(wgB[(co * NC + ci) * 2 + 1], xc, g[j]);
            }
        }

        float v[4];
#pragma unroll
        for (int j = 0; j < 4; j++) {
            float outv = tanh_f(f[j]) * sigm_f(g[j]);
            v[j] = hc[c0 + j] + outv;
        }
        nt_store4(hout + (size_t)pos * NC + c0, v[0], v[1], v[2], v[3]);
    }
}

// Transpose wo (256x64) -> woT (64x256). (FROZEN)
__global__ __launch_bounds__(256) void k_prep_t(
    const float* __restrict__ wo, float* __restrict__ woT)
{
    int t = blockIdx.x * 256 + threadIdx.x;   // 16384 elements
    int k = t >> 6;          // 0..255
    int j = t & 63;          // 0..63
    woT[j * 256 + k] = wo[k * 64 + j];
}

// Head v4 (byte-identical to round 18 — FROZEN)
__global__ __launch_bounds__(512, 4) void k_final(
    const float* __restrict__ hfin, const float* __restrict__ x,
    const int* __restrict__ lengths,
    const float* __restrict__ wa, const float* __restrict__ ba,
    const float* __restrict__ woT, const float* __restrict__ bo,
    float* __restrict__ out)
{
    __shared__ float s_r[64][17];
    __shared__ float s_ra[64][65];
    __shared__ float s_red[2][8][64];

    int t = threadIdx.x;
    int p = t & 63;
    int q = __builtin_amdgcn_readfirstlane(t >> 6);
    int blk = blockIdx.x;
    int b = blk >> 9;
    int n0 = (blk & 511) << 6;
    int n = n0 + p;
    size_t pos = (size_t)b * NSEQ + n;
    float xin = x[pos] * (1.f / 32768.f);

    if (q < 4) {
        const float4* ph = (const float4*)(hfin + pos * NC);
        float4 v = ph[q];
        s_r[p][q * 4 + 0] = fmaxf(v.x - xin, 0.f);
        s_r[p][q * 4 + 1] = fmaxf(v.y - xin, 0.f);
        s_r[p][q * 4 + 2] = fmaxf(v.z - xin, 0.f);
        s_r[p][q * 4 + 3] = fmaxf(v.w - xin, 0.f);
    }
    __syncthreads();

    {
        float r[NC];
#pragma unroll
        for (int c = 0; c < NC; c++) r[c] = s_r[p][c];
#pragma unroll
        for (int jj = 0; jj < 8; jj++) {
            int j = q * 8 + jj;
            float acc = ba[j];
#pragma unroll
            for (int c = 0; c < NC; c++) acc = fmaf(wa[j * NC + c], r[c], acc);
            s_ra[p][j] = fmaxf(acc, 0.f);
        }
    }
    __syncthreads();

    float o[32];
#pragma unroll
    for (int kk = 0; kk < 32; kk++) o[kk] = bo[q * 32 + kk];

#pragma unroll 8
    for (int j = 0; j < 64; j++) {
        float rj = s_ra[p][j];
        const float* wcol = woT + j * 256 + q * 32;
#pragma unroll
        for (int kk = 0; kk < 32; kk++)
            o[kk] = fmaf(wcol[kk], rj, o[kk]);
    }

    float m = -1e30f;
#pragma unroll
    for (int kk = 0; kk < 32; kk++) m = fmaxf(m, o[kk]);
    s_red[0][q][p] = m;
    __syncthreads();
    m = fmaxf(fmaxf(fmaxf(s_red[0][0][p], s_red[0][1][p]),
                    fmaxf(s_red[0][2][p], s_red[0][3][p])),
              fmaxf(fmaxf(s_red[0][4][p], s_red[0][5][p]),
                    fmaxf(s_red[0][6][p], s_red[0][7][p])));
    float s = 0.f;
#pragma unroll
    for (int kk = 0; kk < 32; kk++) s += __expf(o[kk] - m);
    s_red[1][q][p] = s;
    __syncthreads();
    s = ((s_red[1][0][p] + s_red[1][1][p]) + (s_red[1][2][p] + s_red[1][3][p]))
      + ((s_red[1][4][p] + s_red[1][5][p]) + (s_red[1][6][p] + s_red[1][7][p]));
    float lse = m + __logf(s);

    bool valid = n < lengths[b];
    float* po = out + ((size_t)b * 256 + q * 32) * NSEQ + n;
#pragma unroll
    for (int kk = 0; kk < 32; kk++) {
        float v = valid ? (o[kk] - lse) : 0.f;
        __builtin_nontemporal_store(v, &po[(size_t)kk * NSEQ]);
    }
}

extern "C" void kernel_launch(void* const* d_in, const int* in_sizes, int n_in,
                              void* d_out, int out_size, void* d_ws, size_t ws_size,
                              hipStream_t stream) {
    const float* x   = (const float*)d_in[0];
    const int* lens  = (const int*)d_in[1];
    const float* w0  = (const float*)d_in[2];
    const float* b0  = (const float*)d_in[3];
    const float* wf  = (const float*)d_in[4];
    const float* bf  = (const float*)d_in[5];
    const float* wg  = (const float*)d_in[6];
    const float* bg  = (const float*)d_in[7];
    const float* wa  = (const float*)d_in[8];
    const float* ba  = (const float*)d_in[9];
    const float* wo  = (const float*)d_in[10];
    const float* bo  = (const float*)d_in[11];
    float* out = (float*)d_out;

    float* hA = (float*)d_ws;                          // [B][N][16] (16 MiB)
    float* hB = hA + (size_t)NB * NSEQ * NC;           // ping-pong (32 MiB total)
    float* woT = hB + (size_t)NB * NSEQ * NC;          // 64 KiB transposed wo

    auto WF = [&](int i) { return wf + (size_t)(i - 1) * NC * NC * 2; };
    auto BF = [&](int i) { return bf + (size_t)(i - 1) * NC; };
    auto WG = [&](int i) { return wg + (size_t)(i - 1) * NC * NC * 2; };
    auto BG = [&](int i) { return bg + (size_t)(i - 1) * NC; };
    auto D  = [&](int i) { return 1 << (i % 10); };

    k_prep_t<<<dim3(64), dim3(256), 0, stream>>>(wo, woT);
    k_layer0<<<dim3(LBLK), dim3(256), 0, stream>>>(x, w0, b0, hA);

    float* cur = hA;
    float* nxt = hB;
    auto single = [&](int i) {
        k_layer<<<dim3(QGRD), dim3(256), 0, stream>>>(cur, nxt,
            WF(i), BF(i), WG(i), BG(i), D(i));
        float* tmp = cur; cur = nxt; nxt = tmp;
    };
    auto pair = [&](int iA, int iB) {
        k_pair<<<dim3(QGRD), dim3(256), 0, stream>>>(cur, nxt,
            WF(iA), BF(iA), WG(iA), BG(iA), D(iA),
            WF(iB), BF(iB), WG(iB), BG(iB), D(iB));
        float* tmp = cur; cur = nxt; nxt = tmp;
    };

    pair(1, 2);
    pair(3, 4);
    single(5);
    single(6);
    single(7);
    single(8);
    pair(9, 10);
    pair(11, 12);
    pair(13, 14);
    single(15);
    single(16);
    single(17);
    single(18);
    pair(19, 20);
    pair(21, 22);
    pair(23, 24);
    single(25);
    single(26);
    single(27);
    single(28);
    single(29);

    dim3 fgrd(NB * (NSEQ / 64));
    k_final<<<fgrd, dim3(512), 0, stream>>>(cur, x, lens, wa, ba, woT, bo, out);
}

// Round 20
// 576.801 us; speedup vs baseline: 1.2306x; 1.2306x over previous
//
#include <hip/hip_runtime.h>

#define NSEQ 32768
#define NB 8
#define NC 16
#define LBLK 1024          // layer0 grid (NB*NSEQ/256)
#define LPX (LBLK / 8)     // layer0 logical blocks per XCD = 128
#define QGRD 4096          // gated-layer grid (NB*NSEQ/64), 4 threads/position
#define QPX (QGRD / 8)     // gated-layer logical blocks per XCD = 512

typedef float vfloat4 __attribute__((ext_vector_type(4)));   // native vec for nontemporal builtin

__device__ __forceinline__ float sigm_f(float x) {
    return __fdividef(1.f, 1.f + __expf(-x));
}
__device__ __forceinline__ float tanh_f(float x) {
    return __fdividef(2.f, 1.f + __expf(-2.f * x)) - 1.f;
}

__device__ __forceinline__ void nt_store4(float* p, float a, float b, float c, float d) {
    vfloat4 v; v.x = a; v.y = b; v.z = c; v.w = d;
    __builtin_nontemporal_store(v, (vfloat4*)p);
}

// Layer 0 (byte-identical to round 18 — FROZEN)
__global__ __launch_bounds__(256) void k_layer0(
    const float* __restrict__ x, const float* __restrict__ w0,
    const float* __restrict__ b0, float* __restrict__ h)
{
    int bid = blockIdx.x;
    int tid = ((bid & 7) * LPX + (bid >> 3)) * 256 + threadIdx.x;
    int n = tid & (NSEQ - 1);
    const float inv = 1.f / 32768.f;
    float xc = x[tid] * inv;
    float xp = (n >= 1) ? x[tid - 1] * inv : 0.f;
    float v[NC];
#pragma unroll
    for (int c = 0; c < NC; c++) {
        float o = w0[c * 2] * xp + w0[c * 2 + 1] * xc + b0[c];
        v[c] = xc + o;
    }
    float* ph = h + (size_t)tid * NC;
#pragma unroll
    for (int i = 0; i < 4; i++)
        nt_store4(ph + i * 4, v[i * 4], v[i * 4 + 1], v[i * 4 + 2], v[i * 4 + 3]);
}

// Gated layer (byte-identical to round 18 — FROZEN)
__global__ __launch_bounds__(256, 6) void k_layer(
    const float* __restrict__ hin, float* __restrict__ hout,
    const float* __restrict__ wf, const float* __restrict__ bf,
    const float* __restrict__ wg, const float* __restrict__ bg, int d)
{
    int bid = blockIdx.x;
    int lbid = (bid & 7) * QPX + (bid >> 3);          // XCD swizzle: batch b -> XCD b
    int t = threadIdx.x;
    int pos = lbid * 64 + (t & 63);                   // position over B*N
    int q = __builtin_amdgcn_readfirstlane(t >> 6);   // channel quarter 0..3
    int n = pos & (NSEQ - 1);

    float hc[NC], hp[NC];
    {
        const float4* pc = (const float4*)(hin + (size_t)pos * NC);
#pragma unroll
        for (int i = 0; i < 4; i++) {
            float4 tv = pc[i];
            hc[i * 4] = tv.x; hc[i * 4 + 1] = tv.y; hc[i * 4 + 2] = tv.z; hc[i * 4 + 3] = tv.w;
        }
    }
    if (n >= d) {
        const float4* pp = (const float4*)(hin + (size_t)(pos - d) * NC);
#pragma unroll
        for (int i = 0; i < 4; i++) {
            float4 tv = pp[i];
            hp[i * 4] = tv.x; hp[i * 4 + 1] = tv.y; hp[i * 4 + 2] = tv.z; hp[i * 4 + 3] = tv.w;
        }
    } else {
#pragma unroll
        for (int i = 0; i < NC; i++) hp[i] = 0.f;
    }

    const int c0 = q * 4;
    float f[4], g[4];
#pragma unroll
    for (int j = 0; j < 4; j++) { f[j] = bf[c0 + j]; g[j] = bg[c0 + j]; }

#pragma unroll
    for (int ci = 0; ci < NC; ci++) {
        float xp = hp[ci], xc = hc[ci];
#pragma unroll
        for (int j = 0; j < 4; j++) {
            int co = c0 + j;
            // weights wave-uniform -> scalar loads, SGPR operand per v_fma
            f[j] = fmaf(wf[(co * NC + ci) * 2 + 0], xp, f[j]);
            f[j] = fmaf(wf[(co * NC + ci) * 2 + 1], xc, f[j]);
            g[j] = fmaf(wg[(co * NC + ci) * 2 + 0], xp, g[j]);
            g[j] = fmaf(wg[(co * NC + ci) * 2 + 1], xc, g[j]);
        }
    }

    float v[4];
#pragma unroll
    for (int j = 0; j < 4; j++) {
        float outv = tanh_f(f[j]) * sigm_f(g[j]);
        v[j] = hc[c0 + j] + outv;
    }
    nt_store4(hout + (size_t)pos * NC + c0, v[0], v[1], v[2], v[3]);
}

// Transpose wo (256x64) -> woT (64x256). Pure data movement. (FROZEN)
__global__ __launch_bounds__(256) void k_prep_t(
    const float* __restrict__ wo, float* __restrict__ woT)
{
    int t = blockIdx.x * 256 + threadIdx.x;   // 16384 elements
    int k = t >> 6;          // 0..255
    int j = t & 63;          // 0..63
    woT[j * 256 + k] = wo[k * 64 + j];
}

// Head v4 (byte-identical to round 18 — FROZEN)
__global__ __launch_bounds__(512, 4) void k_final(
    const float* __restrict__ hfin, const float* __restrict__ x,
    const int* __restrict__ lengths,
    const float* __restrict__ wa, const float* __restrict__ ba,
    const float* __restrict__ woT, const float* __restrict__ bo,
    float* __restrict__ out)
{
    __shared__ float s_r[64][17];    // relu(agg), odd stride: conflict-free
    __shared__ float s_ra[64][65];   // relu(a), odd stride
    __shared__ float s_red[2][8][64];

    int t = threadIdx.x;
    int p = t & 63;
    int q = __builtin_amdgcn_readfirstlane(t >> 6);   // wave index 0..7, scalar
    int blk = blockIdx.x;
    int b = blk >> 9;                 // 512 tiles of 64 per batch
    int n0 = (blk & 511) << 6;
    int n = n0 + p;
    size_t pos = (size_t)b * NSEQ + n;
    float xin = x[pos] * (1.f / 32768.f);

    // phase 1: waves 0-3 stage relu(h - xin) (identical math text)
    if (q < 4) {
        const float4* ph = (const float4*)(hfin + pos * NC);
        float4 v = ph[q];
        s_r[p][q * 4 + 0] = fmaxf(v.x - xin, 0.f);
        s_r[p][q * 4 + 1] = fmaxf(v.y - xin, 0.f);
        s_r[p][q * 4 + 2] = fmaxf(v.z - xin, 0.f);
        s_r[p][q * 4 + 3] = fmaxf(v.w - xin, 0.f);
    }
    __syncthreads();

    // phase 2: a[j] for j = q*8 .. q*8+7 (same per-j fmaf chain)
    {
        float r[NC];
#pragma unroll
        for (int c = 0; c < NC; c++) r[c] = s_r[p][c];
#pragma unroll
        for (int jj = 0; jj < 8; jj++) {
            int j = q * 8 + jj;
            float acc = ba[j];
#pragma unroll
            for (int c = 0; c < NC; c++) acc = fmaf(wa[j * NC + c], r[c], acc);
            s_ra[p][j] = fmaxf(acc, 0.f);
        }
    }
    __syncthreads();

    // phase 3 (j-outer): o[kk] for k = q*32+kk; one ds_read of ra per j,
    // 32 fmaf with SGPR weight operand from woT (contiguous, wave-uniform).
    float o[32];
#pragma unroll
    for (int kk = 0; kk < 32; kk++) o[kk] = bo[q * 32 + kk];

#pragma unroll 8
    for (int j = 0; j < 64; j++) {
        float rj = s_ra[p][j];
        const float* wcol = woT + j * 256 + q * 32;
#pragma unroll
        for (int kk = 0; kk < 32; kk++)
            o[kk] = fmaf(wcol[kk], rj, o[kk]);
    }

    float m = -1e30f;
#pragma unroll
    for (int kk = 0; kk < 32; kk++) m = fmaxf(m, o[kk]);
    s_red[0][q][p] = m;
    __syncthreads();
    m = fmaxf(fmaxf(fmaxf(s_red[0][0][p], s_red[0][1][p]),
                    fmaxf(s_red[0][2][p], s_red[0][3][p])),
              fmaxf(fmaxf(s_red[0][4][p], s_red[0][5][p]),
                    fmaxf(s_red[0][6][p], s_red[0][7][p])));
    float s = 0.f;
#pragma unroll
    for (int kk = 0; kk < 32; kk++) s += __expf(o[kk] - m);
    s_red[1][q][p] = s;
    __syncthreads();
    s = ((s_red[1][0][p] + s_red[1][1][p]) + (s_red[1][2][p] + s_red[1][3][p]))
      + ((s_red[1][4][p] + s_red[1][5][p]) + (s_red[1][6][p] + s_red[1][7][p]));
    float lse = m + __logf(s);

    bool valid = n < lengths[b];
    float* po = out + ((size_t)b * 256 + q * 32) * NSEQ + n;
#pragma unroll
    for (int kk = 0; kk < 32; kk++) {
        float v = valid ? (o[kk] - lse) : 0.f;
        __builtin_nontemporal_store(v, &po[(size_t)kk * NSEQ]);
    }
}

extern "C" void kernel_launch(void* const* d_in, const int* in_sizes, int n_in,
                              void* d_out, int out_size, void* d_ws, size_t ws_size,
                              hipStream_t stream) {
    const float* x   = (const float*)d_in[0];
    const int* lens  = (const int*)d_in[1];
    const float* w0  = (const float*)d_in[2];
    const float* b0  = (const float*)d_in[3];
    const float* wf  = (const float*)d_in[4];
    const float* bf  = (const float*)d_in[5];
    const float* wg  = (const float*)d_in[6];
    const float* bg  = (const float*)d_in[7];
    const float* wa  = (const float*)d_in[8];
    const float* ba  = (const float*)d_in[9];
    const float* wo  = (const float*)d_in[10];
    const float* bo  = (const float*)d_in[11];
    float* out = (float*)d_out;

    float* hA = (float*)d_ws;                          // [B][N][16] (16 MiB)
    float* hB = hA + (size_t)NB * NSEQ * NC;           // ping-pong (32 MiB total)
    float* woT = hB + (size_t)NB * NSEQ * NC;          // 64 KiB transposed wo

    k_prep_t<<<dim3(64), dim3(256), 0, stream>>>(wo, woT);
    k_layer0<<<dim3(LBLK), dim3(256), 0, stream>>>(x, w0, b0, hA);

    float* cur = hA;
    float* nxt = hB;
    for (int i = 1; i <= 29; i++) {
        int d = 1 << (i % 10);
        k_layer<<<dim3(QGRD), dim3(256), 0, stream>>>(cur, nxt,
                                         wf + (size_t)(i - 1) * NC * NC * 2,
                                         bf + (size_t)(i - 1) * NC,
                                         wg + (size_t)(i - 1) * NC * NC * 2,
                                         bg + (size_t)(i - 1) * NC, d);
        float* tmp = cur; cur = nxt; nxt = tmp;
    }

    dim3 fgrd(NB * (NSEQ / 64));
    k_final<<<fgrd, dim3(512), 0, stream>>>(cur, x, lens, wa, ba, woT, bo, out);
}